// Round 18
// baseline (134.897 us; speedup 1.0000x reference)
//
#include <hip/hip_runtime.h>
#include <hip/hip_bf16.h>

#define N_NODES 8192
#define E_EDGES 262144
#define R_REL   2
#define F_FEAT  111
#define D_EMB   32
#define H_HID   256
#define C_CLS   15
#define DCAP2   96      // fixed capacity per (rel,dst) row in colD2 (Poisson(32), P(>=96)~1e-19)
#define SCAP    96      // fixed capacity per (rel,src) row in colS2
#define BMW     256     // bitmap words per row (8192 bits)

// deg layout: [0,2N) = dedup'd src counts (filled by k_dedup_mean), [2N,4N) = raw dst counts

// ---------------- K0: fast zero of deg/xp/G1 ----------------
__global__ void k_zero(float4* __restrict__ p, int n4) {
    int i = blockIdx.x * blockDim.x + threadIdx.x;
    if (i < n4) p[i] = make_float4(0.f, 0.f, 0.f, 0.f);
}

// ---------------- K1: fused prep: embed | edge append (4 edges/thread, ILP) | W96 concat ----------------
__global__ void k_prep(const float* __restrict__ x_note, const float* __restrict__ W,
                       const float* __restrict__ b, float* __restrict__ X0,
                       const int* __restrict__ edges, int* __restrict__ deg,
                       int* __restrict__ colD2,
                       const float* __restrict__ Wself, const float* __restrict__ Wneigh,
                       float* __restrict__ W96) {
    int blk = blockIdx.x;
    if (blk < 1024) {
        __shared__ float Ws[F_FEAT * D_EMB];
        for (int i = threadIdx.x; i < F_FEAT * D_EMB; i += blockDim.x) Ws[i] = W[i];
        __syncthreads();
        int tid = blk * 256 + threadIdx.x;
        int n = tid >> 5, d = tid & 31;
        const float* xr = x_note + n * F_FEAT;
        float acc = b[d];
        for (int f = 0; f < F_FEAT; ++f) acc += xr[f] * Ws[f * D_EMB + d];
        X0[n * D_EMB + d] = acc;
    } else if (blk < 1024 + 512) {
        // 512 tiles x 1024 edges; 4 independent atomic->write chains per thread
        int tile = (blk - 1024) * 1024;               // global edge index base
        int r = tile >> 18;                            // uniform per tile (E=2^18)
        int e0 = (tile & (E_EDGES - 1)) + threadIdx.x;
        const int* srcp = edges + (r * 2) * E_EDGES;
        const int* dstp = edges + (r * 2 + 1) * E_EDGES;
        int s0 = srcp[e0], s1 = srcp[e0 + 256], s2 = srcp[e0 + 512], s3 = srcp[e0 + 768];
        int d0 = dstp[e0], d1 = dstp[e0 + 256], d2 = dstp[e0 + 512], d3 = dstp[e0 + 768];
        int* degD = deg + (2 + r) * N_NODES;
        int p0 = atomicAdd(&degD[d0], 1);
        int p1 = atomicAdd(&degD[d1], 1);
        int p2 = atomicAdd(&degD[d2], 1);
        int p3 = atomicAdd(&degD[d3], 1);
        int* colR = colD2 + (size_t)r * N_NODES * DCAP2;
        if (p0 < DCAP2) colR[d0 * DCAP2 + p0] = s0;
        if (p1 < DCAP2) colR[d1 * DCAP2 + p1] = s1;
        if (p2 < DCAP2) colR[d2 * DCAP2 + p2] = s2;
        if (p3 < DCAP2) colR[d3 * DCAP2 + p3] = s3;
    } else {
        int i = (blk - 1536) * 256 + threadIdx.x;     // 96*256
        int dd = i >> 8, h = i & 255;
        float v;
        if (dd < 32)      v = Wself[dd * 256 + h] + Wself[(32 + dd) * 256 + h];
        else if (dd < 64) v = Wneigh[(dd - 32) * 256 + h];
        else              v = Wneigh[(32 + dd - 64) * 256 + h];
        W96[i] = v;
    }
}

// ---------------- K2: single-pass per-row: bitmap dedup + append colS2 + X0 mean ----------------
// 4096 blocks x 4 rows; per row 64 lanes. Exact dedup via 8192-bit LDS bitmap.
__global__ __launch_bounds__(256) void k_dedup_mean(const int* __restrict__ deg,   // raw dst counts at [2N,4N)
                                                    const int* __restrict__ colD2,
                                                    int* __restrict__ degS,        // dedup'd src counts at [0,2N)
                                                    int* __restrict__ colS2,
                                                    const float* __restrict__ X0,
                                                    float* __restrict__ xin) {
    __shared__ int buf[4][DCAP2];
    __shared__ unsigned int bm[4][BMW];
    int w = threadIdx.x >> 6, lane = threadIdx.x & 63;
    int row = blockIdx.x * 4 + w;                      // 16384 (r,dst) rows
    int r = row >> 13, n = row & (N_NODES - 1);
    int lenRaw = deg[(2 + r) * N_NODES + n];
    int lim = (lenRaw < DCAP2) ? lenRaw : DCAP2;
    const int* base = colD2 + (r * N_NODES + n) * DCAP2;
    #pragma unroll
    for (int q = 0; q < BMW / 64; ++q) bm[w][lane + q * 64] = 0u;
    for (int i = lane; i < lim; i += 64) buf[w][i] = base[i];
    __syncthreads();
    // dedup + append survivors (one LDS atomicOr per entry, exact)
    for (int i = lane; i < lim; i += 64) {
        int v = buf[w][i];
        unsigned int bit = 1u << (v & 31);
        unsigned int old = atomicOr(&bm[w][v >> 5], bit);
        if (!(old & bit)) {
            int pos = atomicAdd(&degS[r * N_NODES + v], 1);
            if (pos < SCAP) colS2[(r * N_NODES + v) * SCAP + pos] = n;
        }
    }
    // mean over raw entries (duplicates counted), 2 halves of 32 dims
    int d = lane & 31, h = lane >> 5;
    float a0 = 0.f, a1 = 0.f, a2 = 0.f, a3 = 0.f;
    int i = h;
    for (; i + 6 < lim; i += 8) {
        int c0 = buf[w][i], c1 = buf[w][i + 2], c2 = buf[w][i + 4], c3 = buf[w][i + 6];
        a0 += X0[c0 * D_EMB + d]; a1 += X0[c1 * D_EMB + d];
        a2 += X0[c2 * D_EMB + d]; a3 += X0[c3 * D_EMB + d];
    }
    for (; i < lim; i += 2) a0 += X0[buf[w][i] * D_EMB + d];
    float acc = ((a0 + a1) + (a2 + a3));
    acc += __shfl_down(acc, 32, 64);
    if (lane < 32) {
        float inv = 1.f / fmaxf((float)lenRaw, 1.f);
        xin[n * 96 + 32 + r * 32 + d] = acc * inv;
        if (r == 0) xin[n * 96 + d] = X0[n * D_EMB + d];
    }
}

// ---------------- K3: GEMM 64x64x96 + H1 write + G1 fold ----------------
__global__ __launch_bounds__(256) void k_gemm_g1(const float* __restrict__ xin,
                                                 const float* __restrict__ W96,
                                                 const float* __restrict__ bg,
                                                 const float* __restrict__ Ws1,
                                                 float* __restrict__ H1,
                                                 float* __restrict__ G1) {
    __shared__ float As[64][97];
    __shared__ float Bs[96][64];
    int g = blockIdx.x;
    int bm = g >> 2, bn = g & 3;
    int t = threadIdx.x;
    int nb = bm * 64, cb = bn * 64;
    for (int i = t; i < 64 * 96; i += 256) { int row = i / 96, k = i - row * 96; As[row][k] = xin[(nb + row) * 96 + k]; }
    for (int i = t; i < 96 * 64; i += 256) { int k = i >> 6, col = i & 63; Bs[k][col] = W96[k * 256 + cb + col]; }
    __syncthreads();
    int tx = t & 15, ty = t >> 4;
    float acc[4][4] = {};
    #pragma unroll 4
    for (int k = 0; k < 96; ++k) {
        float a0 = As[ty * 4 + 0][k], a1 = As[ty * 4 + 1][k], a2 = As[ty * 4 + 2][k], a3 = As[ty * 4 + 3][k];
        float b0 = Bs[k][tx * 4 + 0], b1 = Bs[k][tx * 4 + 1], b2 = Bs[k][tx * 4 + 2], b3 = Bs[k][tx * 4 + 3];
        acc[0][0] += a0 * b0; acc[0][1] += a0 * b1; acc[0][2] += a0 * b2; acc[0][3] += a0 * b3;
        acc[1][0] += a1 * b0; acc[1][1] += a1 * b1; acc[1][2] += a1 * b2; acc[1][3] += a1 * b3;
        acc[2][0] += a2 * b0; acc[2][1] += a2 * b1; acc[2][2] += a2 * b2; acc[2][3] += a2 * b3;
        acc[3][0] += a3 * b0; acc[3][1] += a3 * b1; acc[3][2] += a3 * b2; acc[3][3] += a3 * b3;
    }
    float hv[4][4];
    #pragma unroll
    for (int i = 0; i < 4; ++i) {
        int n = nb + ty * 4 + i;
        #pragma unroll
        for (int j = 0; j < 4; ++j) {
            int c = cb + tx * 4 + j;
            hv[i][j] = fmaxf(acc[i][j] + bg[c] + bg[H_HID + c], 0.f);
            H1[n * H_HID + c] = hv[i][j];
        }
    }
    __syncthreads();
    float* Wg = &Bs[0][0];                 // reuse Bs as [64][16]
    #pragma unroll
    for (int i = 0; i < 4; ++i)
        #pragma unroll
        for (int j = 0; j < 4; ++j)
            As[ty * 4 + i][tx * 4 + j] = hv[i][j];
    for (int idx = t; idx < 64 * C_CLS; idx += 256) {
        int j = idx / C_CLS, c = idx - j * C_CLS;
        Wg[j * 16 + c] = Ws1[(cb + j) * C_CLS + c];
    }
    __syncthreads();
    for (int task = t; task < 64 * C_CLS; task += 256) {
        int row = task / C_CLS, c = task - row * C_CLS;
        float s = 0.f;
        #pragma unroll 8
        for (int j = 0; j < 64; ++j) s += As[row][j] * Wg[j * 16 + c];
        atomicAdd(&G1[(nb + row) * 16 + c], s);
    }
}

// ---------------- K4: logits via colS2 gather of G1 (unroll-8); softmax -> S1 + padded S1p ----------------
__global__ __launch_bounds__(256) void k_logits_sm(const int* __restrict__ deg,
                                                   const int* __restrict__ colS2,
                                                   const float* __restrict__ G1,
                                                   float* __restrict__ S1,
                                                   float* __restrict__ S1p) {
    int n = (blockIdx.x * blockDim.x + threadIdx.x) >> 4;   // node (as src)
    int c = threadIdx.x & 15;
    float a0 = 0.f, a1 = 0.f, a2 = 0.f, a3 = 0.f, a4 = 0.f, a5 = 0.f, a6 = 0.f, a7 = 0.f;
    for (int r = 0; r < R_REL; ++r) {
        int len = deg[r * N_NODES + n];
        if (len > SCAP) len = SCAP;
        const int* cr = colS2 + (r * N_NODES + n) * SCAP;
        int idx = 0;
        for (; idx + 8 <= len; idx += 8) {
            int c0 = cr[idx + 0], c1 = cr[idx + 1], c2 = cr[idx + 2], c3 = cr[idx + 3];
            int c4 = cr[idx + 4], c5 = cr[idx + 5], c6 = cr[idx + 6], c7 = cr[idx + 7];
            a0 += G1[c0 * 16 + c]; a1 += G1[c1 * 16 + c];
            a2 += G1[c2 * 16 + c]; a3 += G1[c3 * 16 + c];
            a4 += G1[c4 * 16 + c]; a5 += G1[c5 * 16 + c];
            a6 += G1[c6 * 16 + c]; a7 += G1[c7 * 16 + c];
        }
        for (; idx < len; ++idx) a0 += G1[cr[idx] * 16 + c];
    }
    float logit = (c < C_CLS) ? (((a0 + a1) + (a2 + a3)) + ((a4 + a5) + (a6 + a7))) : -1e30f;
    float m = logit;
    for (int off = 8; off; off >>= 1) m = fmaxf(m, __shfl_xor(m, off, 16));
    float e = (c < C_CLS) ? expf(logit - m) : 0.f;
    float ssum = e;
    for (int off = 8; off; off >>= 1) ssum += __shfl_xor(ssum, off, 16);
    float p = e / ssum;
    if (c < C_CLS) S1[n * C_CLS + c] = p;
    S1p[n * 16 + c] = (c < C_CLS) ? p : 0.f;
}

// ---------------- K5: fused xp (blocks 0..127) | T + adjp partials (blocks 128..639) ----------------
__global__ __launch_bounds__(256) void k_xpT(const float* __restrict__ S1p, const float* __restrict__ H1,
                                             float* __restrict__ xp,
                                             const int* __restrict__ deg, const int* __restrict__ colS2,
                                             float* __restrict__ partial) {
    __shared__ float Tl[16][16];
    int blk = blockIdx.x;
    if (blk < 128) {
        int h = threadIdx.x;
        int base = blk * 64;
        float acc[C_CLS];
        #pragma unroll
        for (int c = 0; c < C_CLS; ++c) acc[c] = 0.f;
        for (int i = 0; i < 64; ++i) {
            int n = base + i;
            float hv = H1[n * H_HID + h];
            const float* sr = S1p + n * 16;
            #pragma unroll
            for (int c = 0; c < C_CLS; ++c) acc[c] += sr[c] * hv;
        }
        #pragma unroll
        for (int c = 0; c < C_CLS; ++c) atomicAdd(&xp[c * H_HID + h], acc[c]);
    } else {
        int bb = blk - 128;                     // 512 blocks, 16 nodes each
        int g = threadIdx.x >> 4, c = threadIdx.x & 15;
        int n0 = bb * 16;
        int n = n0 + g;
        float a0 = 0.f, a1 = 0.f, a2 = 0.f, a3 = 0.f, a4 = 0.f, a5 = 0.f, a6 = 0.f, a7 = 0.f;
        for (int r = 0; r < R_REL; ++r) {
            int len = deg[r * N_NODES + n];
            if (len > SCAP) len = SCAP;
            const int* cr = colS2 + (r * N_NODES + n) * SCAP;
            int idx = 0;
            for (; idx + 8 <= len; idx += 8) {
                int c0 = cr[idx + 0], c1 = cr[idx + 1], c2 = cr[idx + 2], c3 = cr[idx + 3];
                int c4 = cr[idx + 4], c5 = cr[idx + 5], c6 = cr[idx + 6], c7 = cr[idx + 7];
                a0 += S1p[c0 * 16 + c]; a1 += S1p[c1 * 16 + c];
                a2 += S1p[c2 * 16 + c]; a3 += S1p[c3 * 16 + c];
                a4 += S1p[c4 * 16 + c]; a5 += S1p[c5 * 16 + c];
                a6 += S1p[c6 * 16 + c]; a7 += S1p[c7 * 16 + c];
            }
            for (; idx < len; ++idx) a0 += S1p[cr[idx] * 16 + c];
        }
        float tval = ((a0 + a1) + (a2 + a3)) + ((a4 + a5) + (a6 + a7));
        Tl[g][c] = (c < C_CLS) ? tval : 0.f;
        __syncthreads();
        int t = threadIdx.x;
        if (t < C_CLS * C_CLS) {
            int k = t / C_CLS, cc = t - k * C_CLS;
            float s = 0.f;
            #pragma unroll
            for (int i = 0; i < 16; ++i) s += S1p[(n0 + i) * 16 + k] * Tl[i][cc];
            partial[bb * (C_CLS * C_CLS) + t] = s;
        }
    }
}

// ---------------- K6: second cluster (one block; sums 512 partials, 16-wide ILP) ----------------
__global__ void k_cluster2(const float* __restrict__ partialAdj, const float* __restrict__ xp,
                           const float* __restrict__ Ws2, float* __restrict__ out_x,
                           float* __restrict__ out_S2) {
    __shared__ float a2[C_CLS * C_CLS];
    __shared__ float xps[C_CLS * H_HID];
    __shared__ float y2[C_CLS * H_HID];
    __shared__ float lg[C_CLS * C_CLS];
    __shared__ float S2s[C_CLS * C_CLS];
    int t = threadIdx.x;   // 256 = H_HID
    if (t < C_CLS * C_CLS) {
        float s0 = 0.f, s1 = 0.f, s2 = 0.f, s3 = 0.f;
        float s4 = 0.f, s5 = 0.f, s6 = 0.f, s7 = 0.f;
        float s8 = 0.f, s9 = 0.f, sA = 0.f, sB = 0.f;
        float sC = 0.f, sD = 0.f, sE = 0.f, sF = 0.f;
        #define PA(k) partialAdj[(b + k) * (C_CLS * C_CLS) + t]
        for (int b = 0; b < 512; b += 16) {
            s0 += PA(0);  s1 += PA(1);  s2 += PA(2);  s3 += PA(3);
            s4 += PA(4);  s5 += PA(5);  s6 += PA(6);  s7 += PA(7);
            s8 += PA(8);  s9 += PA(9);  sA += PA(10); sB += PA(11);
            sC += PA(12); sD += PA(13); sE += PA(14); sF += PA(15);
        }
        #undef PA
        a2[t] = (((s0 + s1) + (s2 + s3)) + ((s4 + s5) + (s6 + s7)))
              + (((s8 + s9) + (sA + sB)) + ((sC + sD) + (sE + sF)));
    }
    for (int i = t; i < C_CLS * H_HID; i += 256) xps[i] = xp[i];
    __syncthreads();
    for (int i = 0; i < C_CLS; ++i) {
        float acc = 0.f;
        #pragma unroll
        for (int j = 0; j < C_CLS; ++j) acc += a2[i * C_CLS + j] * xps[j * H_HID + t];
        y2[i * H_HID + t] = acc;
    }
    __syncthreads();
    for (int idx = t; idx < C_CLS * C_CLS; idx += 256) {
        int i = idx / C_CLS, c = idx % C_CLS;
        float acc = 0.f;
        for (int h = 0; h < H_HID; ++h) acc += y2[i * H_HID + h] * Ws2[h * C_CLS + c];
        lg[idx] = acc;
    }
    __syncthreads();
    if (t < C_CLS) {
        float m = -1e30f;
        for (int c = 0; c < C_CLS; ++c) m = fmaxf(m, lg[t * C_CLS + c]);
        float s = 0.f;
        for (int c = 0; c < C_CLS; ++c) { float ev = expf(lg[t * C_CLS + c] - m); S2s[t * C_CLS + c] = ev; s += ev; }
        for (int c = 0; c < C_CLS; ++c) { S2s[t * C_CLS + c] /= s; out_S2[t * C_CLS + c] = S2s[t * C_CLS + c]; }
    }
    __syncthreads();
    for (int c = 0; c < C_CLS; ++c) {
        float acc = 0.f;
        #pragma unroll
        for (int i = 0; i < C_CLS; ++i) acc += S2s[i * C_CLS + c] * xps[i * H_HID + t];
        out_x[c * H_HID + t] = acc;
    }
}

extern "C" void kernel_launch(void* const* d_in, const int* in_sizes, int n_in,
                              void* d_out, int out_size, void* d_ws, size_t ws_size,
                              hipStream_t stream) {
    const float* x_note  = (const float*)d_in[0];
    const int*   edges   = (const int*)d_in[1];
    const float* W_embed = (const float*)d_in[2];
    const float* b_embed = (const float*)d_in[3];
    const float* W_self  = (const float*)d_in[4];
    const float* W_neigh = (const float*)d_in[5];
    const float* b_gnn   = (const float*)d_in[6];
    const float* W_s1    = (const float*)d_in[7];
    const float* W_s2    = (const float*)d_in[8];
    float* out = (float*)d_out;

    float* out_x  = out;
    float* out_S1 = out + C_CLS * H_HID;
    float* out_S2 = out + C_CLS * H_HID + N_NODES * C_CLS;

    // Region (18MB), time-multiplexed:
    //   [0:8MB)    colD2 (6MB, dead after k_dedup_mean) -> H1 (8MB, from k_gemm_g1 on)
    //   [8:14MB)   colS2
    //   [14:14.5)  S1p
    //   [14.5:17.5) xin (dead after k_gemm_g1)
    char* ws = (char*)d_ws;
    size_t off = 0;
    auto alloc = [&](size_t bytes) { size_t p = off; off += (bytes + 255) & ~(size_t)255; return p; };
    size_t regionA = alloc((size_t)18 * 1024 * 1024);
    size_t oDeg    = alloc((size_t)4 * N_NODES * 4);
    size_t oXp     = alloc((size_t)C_CLS * H_HID * 4);
    size_t oG1     = alloc((size_t)N_NODES * 16 * 4);        // zeroed (atomic-accumulated)
    size_t zeroEnd = off;
    size_t oX0     = alloc((size_t)N_NODES * D_EMB * 4);
    size_t oPart   = alloc((size_t)512 * C_CLS * C_CLS * 4);
    size_t oW96    = alloc((size_t)96 * H_HID * 4);

    int*   colD2  = (int*)(ws + regionA);
    float* H1     = (float*)(ws + regionA);                               // overlays colD2
    int*   colS2  = (int*)(ws + regionA + (size_t)8 * 1024 * 1024);
    float* S1p    = (float*)(ws + regionA + (size_t)14 * 1024 * 1024);
    float* xin    = (float*)(ws + regionA + (size_t)14 * 1024 * 1024 + 512 * 1024);
    int*   deg    = (int*)(ws + oDeg);
    float* xp     = (float*)(ws + oXp);
    float* G1     = (float*)(ws + oG1);
    float* X0     = (float*)(ws + oX0);
    float* partialAdj = (float*)(ws + oPart);
    float* W96    = (float*)(ws + oW96);

    // zero deg/xp/G1 (parallel kernel; rocclr fill is slow for small sizes)
    int n4 = (int)((zeroEnd - oDeg) / 16);
    k_zero<<<(n4 + 255) / 256, 256, 0, stream>>>((float4*)(ws + oDeg), n4);

    k_prep<<<1024 + 512 + 96, 256, 0, stream>>>(x_note, W_embed, b_embed, X0, edges, deg, colD2,
                                                W_self, W_neigh, W96);
    k_dedup_mean<<<4096, 256, 0, stream>>>(deg, colD2, deg, colS2, X0, xin);
    k_gemm_g1<<<512, 256, 0, stream>>>(xin, W96, b_gnn, W_s1, H1, G1);
    k_logits_sm<<<(N_NODES * 16) / 256, 256, 0, stream>>>(deg, colS2, G1, out_S1, S1p);
    k_xpT<<<128 + 512, 256, 0, stream>>>(S1p, H1, xp, deg, colS2, partialAdj);
    k_cluster2<<<1, 256, 0, stream>>>(partialAdj, xp, W_s2, out_x, out_S2);
}

// Round 19
// 132.299 us; speedup vs baseline: 1.0196x; 1.0196x over previous
//
#include <hip/hip_runtime.h>
#include <hip/hip_bf16.h>

#define N_NODES 8192
#define E_EDGES 262144
#define R_REL   2
#define F_FEAT  111
#define D_EMB   32
#define H_HID   256
#define C_CLS   15
#define DCAP2   96      // fixed capacity per (rel,dst) row in colD2 (Poisson(32), P(>=96)~1e-19)
#define SCAP    96      // fixed capacity per (rel,src) row in colS2
#define BMW     256     // bitmap words per row (8192 bits)

// deg layout: [0,2N) = dedup'd src counts (filled by k_dedup_mean), [2N,4N) = raw dst counts

// ---------------- K0: fast zero of deg/xp/G1 ----------------
__global__ void k_zero(float4* __restrict__ p, int n4) {
    int i = blockIdx.x * blockDim.x + threadIdx.x;
    if (i < n4) p[i] = make_float4(0.f, 0.f, 0.f, 0.f);
}

// ---------------- K1: fused prep: embed | edge direct-append into colD2 | W96 concat ----------------
__global__ void k_prep(const float* __restrict__ x_note, const float* __restrict__ W,
                       const float* __restrict__ b, float* __restrict__ X0,
                       const int* __restrict__ edges, int* __restrict__ deg,
                       int* __restrict__ colD2,
                       const float* __restrict__ Wself, const float* __restrict__ Wneigh,
                       float* __restrict__ W96) {
    int blk = blockIdx.x;
    if (blk < 1024) {
        __shared__ float Ws[F_FEAT * D_EMB];
        for (int i = threadIdx.x; i < F_FEAT * D_EMB; i += blockDim.x) Ws[i] = W[i];
        __syncthreads();
        int tid = blk * 256 + threadIdx.x;
        int n = tid >> 5, d = tid & 31;
        const float* xr = x_note + n * F_FEAT;
        float acc = b[d];
        for (int f = 0; f < F_FEAT; ++f) acc += xr[f] * Ws[f * D_EMB + d];
        X0[n * D_EMB + d] = acc;
    } else if (blk < 3072) {
        int i = (blk - 1024) * 256 + threadIdx.x;     // R*E edges
        int r = i >> 18, e = i & (E_EDGES - 1);
        int src = edges[(r * 2) * E_EDGES + e];
        int dst = edges[(r * 2 + 1) * E_EDGES + e];
        int pos = atomicAdd(&deg[(2 + r) * N_NODES + dst], 1);
        if (pos < DCAP2) colD2[(r * N_NODES + dst) * DCAP2 + pos] = src;
    } else {
        int i = (blk - 3072) * 256 + threadIdx.x;     // 96*256
        int dd = i >> 8, h = i & 255;
        float v;
        if (dd < 32)      v = Wself[dd * 256 + h] + Wself[(32 + dd) * 256 + h];
        else if (dd < 64) v = Wneigh[(dd - 32) * 256 + h];
        else              v = Wneigh[(32 + dd - 64) * 256 + h];
        W96[i] = v;
    }
}

// ---------------- K2: single-pass per-row: bitmap dedup + append colS2 + X0 mean ----------------
// 4096 blocks x 4 rows; per row 64 lanes. Exact dedup via 8192-bit LDS bitmap.
__global__ __launch_bounds__(256) void k_dedup_mean(const int* __restrict__ deg,   // raw dst counts at [2N,4N)
                                                    const int* __restrict__ colD2,
                                                    int* __restrict__ degS,        // dedup'd src counts at [0,2N)
                                                    int* __restrict__ colS2,
                                                    const float* __restrict__ X0,
                                                    float* __restrict__ xin) {
    __shared__ int buf[4][DCAP2];
    __shared__ unsigned int bm[4][BMW];
    int w = threadIdx.x >> 6, lane = threadIdx.x & 63;
    int row = blockIdx.x * 4 + w;                      // 16384 (r,dst) rows
    int r = row >> 13, n = row & (N_NODES - 1);
    int lenRaw = deg[(2 + r) * N_NODES + n];
    int lim = (lenRaw < DCAP2) ? lenRaw : DCAP2;
    const int* base = colD2 + (r * N_NODES + n) * DCAP2;
    #pragma unroll
    for (int q = 0; q < BMW / 64; ++q) bm[w][lane + q * 64] = 0u;
    for (int i = lane; i < lim; i += 64) buf[w][i] = base[i];
    __syncthreads();
    // dedup + append survivors (one LDS atomicOr per entry, exact)
    for (int i = lane; i < lim; i += 64) {
        int v = buf[w][i];
        unsigned int bit = 1u << (v & 31);
        unsigned int old = atomicOr(&bm[w][v >> 5], bit);
        if (!(old & bit)) {
            int pos = atomicAdd(&degS[r * N_NODES + v], 1);
            if (pos < SCAP) colS2[(r * N_NODES + v) * SCAP + pos] = n;
        }
    }
    // mean over raw entries (duplicates counted), 2 halves of 32 dims
    int d = lane & 31, h = lane >> 5;
    float a0 = 0.f, a1 = 0.f, a2 = 0.f, a3 = 0.f;
    int i = h;
    for (; i + 6 < lim; i += 8) {
        int c0 = buf[w][i], c1 = buf[w][i + 2], c2 = buf[w][i + 4], c3 = buf[w][i + 6];
        a0 += X0[c0 * D_EMB + d]; a1 += X0[c1 * D_EMB + d];
        a2 += X0[c2 * D_EMB + d]; a3 += X0[c3 * D_EMB + d];
    }
    for (; i < lim; i += 2) a0 += X0[buf[w][i] * D_EMB + d];
    float acc = ((a0 + a1) + (a2 + a3));
    acc += __shfl_down(acc, 32, 64);
    if (lane < 32) {
        float inv = 1.f / fmaxf((float)lenRaw, 1.f);
        xin[n * 96 + 32 + r * 32 + d] = acc * inv;
        if (r == 0) xin[n * 96 + d] = X0[n * D_EMB + d];
    }
}

// ---------------- K3: GEMM 64x64x96 + H1 write + G1 fold ----------------
__global__ __launch_bounds__(256) void k_gemm_g1(const float* __restrict__ xin,
                                                 const float* __restrict__ W96,
                                                 const float* __restrict__ bg,
                                                 const float* __restrict__ Ws1,
                                                 float* __restrict__ H1,
                                                 float* __restrict__ G1) {
    __shared__ float As[64][97];
    __shared__ float Bs[96][64];
    int g = blockIdx.x;
    int bm = g >> 2, bn = g & 3;
    int t = threadIdx.x;
    int nb = bm * 64, cb = bn * 64;
    for (int i = t; i < 64 * 96; i += 256) { int row = i / 96, k = i - row * 96; As[row][k] = xin[(nb + row) * 96 + k]; }
    for (int i = t; i < 96 * 64; i += 256) { int k = i >> 6, col = i & 63; Bs[k][col] = W96[k * 256 + cb + col]; }
    __syncthreads();
    int tx = t & 15, ty = t >> 4;
    float acc[4][4] = {};
    #pragma unroll 4
    for (int k = 0; k < 96; ++k) {
        float a0 = As[ty * 4 + 0][k], a1 = As[ty * 4 + 1][k], a2 = As[ty * 4 + 2][k], a3 = As[ty * 4 + 3][k];
        float b0 = Bs[k][tx * 4 + 0], b1 = Bs[k][tx * 4 + 1], b2 = Bs[k][tx * 4 + 2], b3 = Bs[k][tx * 4 + 3];
        acc[0][0] += a0 * b0; acc[0][1] += a0 * b1; acc[0][2] += a0 * b2; acc[0][3] += a0 * b3;
        acc[1][0] += a1 * b0; acc[1][1] += a1 * b1; acc[1][2] += a1 * b2; acc[1][3] += a1 * b3;
        acc[2][0] += a2 * b0; acc[2][1] += a2 * b1; acc[2][2] += a2 * b2; acc[2][3] += a2 * b3;
        acc[3][0] += a3 * b0; acc[3][1] += a3 * b1; acc[3][2] += a3 * b2; acc[3][3] += a3 * b3;
    }
    float hv[4][4];
    #pragma unroll
    for (int i = 0; i < 4; ++i) {
        int n = nb + ty * 4 + i;
        #pragma unroll
        for (int j = 0; j < 4; ++j) {
            int c = cb + tx * 4 + j;
            hv[i][j] = fmaxf(acc[i][j] + bg[c] + bg[H_HID + c], 0.f);
            H1[n * H_HID + c] = hv[i][j];
        }
    }
    __syncthreads();
    float* Wg = &Bs[0][0];                 // reuse Bs as [64][16]
    #pragma unroll
    for (int i = 0; i < 4; ++i)
        #pragma unroll
        for (int j = 0; j < 4; ++j)
            As[ty * 4 + i][tx * 4 + j] = hv[i][j];
    for (int idx = t; idx < 64 * C_CLS; idx += 256) {
        int j = idx / C_CLS, c = idx - j * C_CLS;
        Wg[j * 16 + c] = Ws1[(cb + j) * C_CLS + c];
    }
    __syncthreads();
    for (int task = t; task < 64 * C_CLS; task += 256) {
        int row = task / C_CLS, c = task - row * C_CLS;
        float s = 0.f;
        #pragma unroll 8
        for (int j = 0; j < 64; ++j) s += As[row][j] * Wg[j * 16 + c];
        atomicAdd(&G1[(nb + row) * 16 + c], s);
    }
}

// ---------------- K4: logits via colS2 gather of G1 (unroll-8); softmax -> S1 + padded S1p ----------------
__global__ __launch_bounds__(256) void k_logits_sm(const int* __restrict__ deg,
                                                   const int* __restrict__ colS2,
                                                   const float* __restrict__ G1,
                                                   float* __restrict__ S1,
                                                   float* __restrict__ S1p) {
    int n = (blockIdx.x * blockDim.x + threadIdx.x) >> 4;   // node (as src)
    int c = threadIdx.x & 15;
    float a0 = 0.f, a1 = 0.f, a2 = 0.f, a3 = 0.f, a4 = 0.f, a5 = 0.f, a6 = 0.f, a7 = 0.f;
    for (int r = 0; r < R_REL; ++r) {
        int len = deg[r * N_NODES + n];
        if (len > SCAP) len = SCAP;
        const int* cr = colS2 + (r * N_NODES + n) * SCAP;
        int idx = 0;
        for (; idx + 8 <= len; idx += 8) {
            int c0 = cr[idx + 0], c1 = cr[idx + 1], c2 = cr[idx + 2], c3 = cr[idx + 3];
            int c4 = cr[idx + 4], c5 = cr[idx + 5], c6 = cr[idx + 6], c7 = cr[idx + 7];
            a0 += G1[c0 * 16 + c]; a1 += G1[c1 * 16 + c];
            a2 += G1[c2 * 16 + c]; a3 += G1[c3 * 16 + c];
            a4 += G1[c4 * 16 + c]; a5 += G1[c5 * 16 + c];
            a6 += G1[c6 * 16 + c]; a7 += G1[c7 * 16 + c];
        }
        for (; idx < len; ++idx) a0 += G1[cr[idx] * 16 + c];
    }
    float logit = (c < C_CLS) ? (((a0 + a1) + (a2 + a3)) + ((a4 + a5) + (a6 + a7))) : -1e30f;
    float m = logit;
    for (int off = 8; off; off >>= 1) m = fmaxf(m, __shfl_xor(m, off, 16));
    float e = (c < C_CLS) ? expf(logit - m) : 0.f;
    float ssum = e;
    for (int off = 8; off; off >>= 1) ssum += __shfl_xor(ssum, off, 16);
    float p = e / ssum;
    if (c < C_CLS) S1[n * C_CLS + c] = p;
    S1p[n * 16 + c] = (c < C_CLS) ? p : 0.f;
}

// ---------------- K5: fused xp (blocks 0..127) | T + adjp partials (blocks 128..639) ----------------
__global__ __launch_bounds__(256) void k_xpT(const float* __restrict__ S1p, const float* __restrict__ H1,
                                             float* __restrict__ xp,
                                             const int* __restrict__ deg, const int* __restrict__ colS2,
                                             float* __restrict__ partial) {
    __shared__ float Tl[16][16];
    int blk = blockIdx.x;
    if (blk < 128) {
        int h = threadIdx.x;
        int base = blk * 64;
        float acc[C_CLS];
        #pragma unroll
        for (int c = 0; c < C_CLS; ++c) acc[c] = 0.f;
        for (int i = 0; i < 64; ++i) {
            int n = base + i;
            float hv = H1[n * H_HID + h];
            const float* sr = S1p + n * 16;
            #pragma unroll
            for (int c = 0; c < C_CLS; ++c) acc[c] += sr[c] * hv;
        }
        #pragma unroll
        for (int c = 0; c < C_CLS; ++c) atomicAdd(&xp[c * H_HID + h], acc[c]);
    } else {
        int bb = blk - 128;                     // 512 blocks, 16 nodes each
        int g = threadIdx.x >> 4, c = threadIdx.x & 15;
        int n0 = bb * 16;
        int n = n0 + g;
        float a0 = 0.f, a1 = 0.f, a2 = 0.f, a3 = 0.f, a4 = 0.f, a5 = 0.f, a6 = 0.f, a7 = 0.f;
        for (int r = 0; r < R_REL; ++r) {
            int len = deg[r * N_NODES + n];
            if (len > SCAP) len = SCAP;
            const int* cr = colS2 + (r * N_NODES + n) * SCAP;
            int idx = 0;
            for (; idx + 8 <= len; idx += 8) {
                int c0 = cr[idx + 0], c1 = cr[idx + 1], c2 = cr[idx + 2], c3 = cr[idx + 3];
                int c4 = cr[idx + 4], c5 = cr[idx + 5], c6 = cr[idx + 6], c7 = cr[idx + 7];
                a0 += S1p[c0 * 16 + c]; a1 += S1p[c1 * 16 + c];
                a2 += S1p[c2 * 16 + c]; a3 += S1p[c3 * 16 + c];
                a4 += S1p[c4 * 16 + c]; a5 += S1p[c5 * 16 + c];
                a6 += S1p[c6 * 16 + c]; a7 += S1p[c7 * 16 + c];
            }
            for (; idx < len; ++idx) a0 += S1p[cr[idx] * 16 + c];
        }
        float tval = ((a0 + a1) + (a2 + a3)) + ((a4 + a5) + (a6 + a7));
        Tl[g][c] = (c < C_CLS) ? tval : 0.f;
        __syncthreads();
        int t = threadIdx.x;
        if (t < C_CLS * C_CLS) {
            int k = t / C_CLS, cc = t - k * C_CLS;
            float s = 0.f;
            #pragma unroll
            for (int i = 0; i < 16; ++i) s += S1p[(n0 + i) * 16 + k] * Tl[i][cc];
            partial[bb * (C_CLS * C_CLS) + t] = s;
        }
    }
}

// ---------------- K6: second cluster (one block; sums 512 partials, 16-wide ILP) ----------------
__global__ void k_cluster2(const float* __restrict__ partialAdj, const float* __restrict__ xp,
                           const float* __restrict__ Ws2, float* __restrict__ out_x,
                           float* __restrict__ out_S2) {
    __shared__ float a2[C_CLS * C_CLS];
    __shared__ float xps[C_CLS * H_HID];
    __shared__ float y2[C_CLS * H_HID];
    __shared__ float lg[C_CLS * C_CLS];
    __shared__ float S2s[C_CLS * C_CLS];
    int t = threadIdx.x;   // 256 = H_HID
    if (t < C_CLS * C_CLS) {
        float s0 = 0.f, s1 = 0.f, s2 = 0.f, s3 = 0.f;
        float s4 = 0.f, s5 = 0.f, s6 = 0.f, s7 = 0.f;
        float s8 = 0.f, s9 = 0.f, sA = 0.f, sB = 0.f;
        float sC = 0.f, sD = 0.f, sE = 0.f, sF = 0.f;
        #define PA(k) partialAdj[(b + k) * (C_CLS * C_CLS) + t]
        for (int b = 0; b < 512; b += 16) {
            s0 += PA(0);  s1 += PA(1);  s2 += PA(2);  s3 += PA(3);
            s4 += PA(4);  s5 += PA(5);  s6 += PA(6);  s7 += PA(7);
            s8 += PA(8);  s9 += PA(9);  sA += PA(10); sB += PA(11);
            sC += PA(12); sD += PA(13); sE += PA(14); sF += PA(15);
        }
        #undef PA
        a2[t] = (((s0 + s1) + (s2 + s3)) + ((s4 + s5) + (s6 + s7)))
              + (((s8 + s9) + (sA + sB)) + ((sC + sD) + (sE + sF)));
    }
    for (int i = t; i < C_CLS * H_HID; i += 256) xps[i] = xp[i];
    __syncthreads();
    for (int i = 0; i < C_CLS; ++i) {
        float acc = 0.f;
        #pragma unroll
        for (int j = 0; j < C_CLS; ++j) acc += a2[i * C_CLS + j] * xps[j * H_HID + t];
        y2[i * H_HID + t] = acc;
    }
    __syncthreads();
    for (int idx = t; idx < C_CLS * C_CLS; idx += 256) {
        int i = idx / C_CLS, c = idx % C_CLS;
        float acc = 0.f;
        for (int h = 0; h < H_HID; ++h) acc += y2[i * H_HID + h] * Ws2[h * C_CLS + c];
        lg[idx] = acc;
    }
    __syncthreads();
    if (t < C_CLS) {
        float m = -1e30f;
        for (int c = 0; c < C_CLS; ++c) m = fmaxf(m, lg[t * C_CLS + c]);
        float s = 0.f;
        for (int c = 0; c < C_CLS; ++c) { float ev = expf(lg[t * C_CLS + c] - m); S2s[t * C_CLS + c] = ev; s += ev; }
        for (int c = 0; c < C_CLS; ++c) { S2s[t * C_CLS + c] /= s; out_S2[t * C_CLS + c] = S2s[t * C_CLS + c]; }
    }
    __syncthreads();
    for (int c = 0; c < C_CLS; ++c) {
        float acc = 0.f;
        #pragma unroll
        for (int i = 0; i < C_CLS; ++i) acc += S2s[i * C_CLS + c] * xps[i * H_HID + t];
        out_x[c * H_HID + t] = acc;
    }
}

extern "C" void kernel_launch(void* const* d_in, const int* in_sizes, int n_in,
                              void* d_out, int out_size, void* d_ws, size_t ws_size,
                              hipStream_t stream) {
    const float* x_note  = (const float*)d_in[0];
    const int*   edges   = (const int*)d_in[1];
    const float* W_embed = (const float*)d_in[2];
    const float* b_embed = (const float*)d_in[3];
    const float* W_self  = (const float*)d_in[4];
    const float* W_neigh = (const float*)d_in[5];
    const float* b_gnn   = (const float*)d_in[6];
    const float* W_s1    = (const float*)d_in[7];
    const float* W_s2    = (const float*)d_in[8];
    float* out = (float*)d_out;

    float* out_x  = out;
    float* out_S1 = out + C_CLS * H_HID;
    float* out_S2 = out + C_CLS * H_HID + N_NODES * C_CLS;

    // Region (18MB), time-multiplexed:
    //   [0:8MB)    colD2 (6MB, dead after k_dedup_mean) -> H1 (8MB, from k_gemm_g1 on)
    //   [8:14MB)   colS2
    //   [14:14.5)  S1p
    //   [14.5:17.5) xin (dead after k_gemm_g1)
    char* ws = (char*)d_ws;
    size_t off = 0;
    auto alloc = [&](size_t bytes) { size_t p = off; off += (bytes + 255) & ~(size_t)255; return p; };
    size_t regionA = alloc((size_t)18 * 1024 * 1024);
    size_t oDeg    = alloc((size_t)4 * N_NODES * 4);
    size_t oXp     = alloc((size_t)C_CLS * H_HID * 4);
    size_t oG1     = alloc((size_t)N_NODES * 16 * 4);        // zeroed (atomic-accumulated)
    size_t zeroEnd = off;
    size_t oX0     = alloc((size_t)N_NODES * D_EMB * 4);
    size_t oPart   = alloc((size_t)512 * C_CLS * C_CLS * 4);
    size_t oW96    = alloc((size_t)96 * H_HID * 4);

    int*   colD2  = (int*)(ws + regionA);
    float* H1     = (float*)(ws + regionA);                               // overlays colD2
    int*   colS2  = (int*)(ws + regionA + (size_t)8 * 1024 * 1024);
    float* S1p    = (float*)(ws + regionA + (size_t)14 * 1024 * 1024);
    float* xin    = (float*)(ws + regionA + (size_t)14 * 1024 * 1024 + 512 * 1024);
    int*   deg    = (int*)(ws + oDeg);
    float* xp     = (float*)(ws + oXp);
    float* G1     = (float*)(ws + oG1);
    float* X0     = (float*)(ws + oX0);
    float* partialAdj = (float*)(ws + oPart);
    float* W96    = (float*)(ws + oW96);

    // zero deg/xp/G1 (parallel kernel; rocclr fill is slow for small sizes)
    int n4 = (int)((zeroEnd - oDeg) / 16);
    k_zero<<<(n4 + 255) / 256, 256, 0, stream>>>((float4*)(ws + oDeg), n4);

    k_prep<<<3168, 256, 0, stream>>>(x_note, W_embed, b_embed, X0, edges, deg, colD2,
                                     W_self, W_neigh, W96);
    k_dedup_mean<<<4096, 256, 0, stream>>>(deg, colD2, deg, colS2, X0, xin);
    k_gemm_g1<<<512, 256, 0, stream>>>(xin, W96, b_gnn, W_s1, H1, G1);
    k_logits_sm<<<(N_NODES * 16) / 256, 256, 0, stream>>>(deg, colS2, G1, out_S1, S1p);
    k_xpT<<<128 + 512, 256, 0, stream>>>(S1p, H1, xp, deg, colS2, partialAdj);
    k_cluster2<<<1, 256, 0, stream>>>(partialAdj, xp, W_s2, out_x, out_S2);
}